// Round 1
// baseline (591.347 us; speedup 1.0000x reference)
//
#include <hip/hip_runtime.h>
#include <hip/hip_bf16.h>

#define NR 8192
#define DIN 512
#define DD 256

typedef __attribute__((ext_vector_type(8))) short short8;
typedef __attribute__((ext_vector_type(4))) float f32x4;
typedef __attribute__((ext_vector_type(4))) int i32x4;

static __device__ __forceinline__ unsigned short f2bf(float x) {
    __hip_bfloat16 b = __float2bfloat16(x);
    return __builtin_bit_cast(unsigned short, b);
}
static __device__ __forceinline__ float bf2f(unsigned short u) {
    unsigned v = ((unsigned)u) << 16;
    return __builtin_bit_cast(float, v);
}

// ---------------------------------------------------------------------------
// K2: h = x @ W^T  (fp32-accurate via hi/lo bf16 split, 3 MFMA terms)
// grid (128, 2), block 256.  Tile 64 rows x 128 cols, BK=64.
// ---------------------------------------------------------------------------
__global__ __launch_bounds__(256) void k_gemm_h(
        const float* __restrict__ x, const float* __restrict__ W,
        float* __restrict__ h) {
    __shared__ unsigned short Ah[64][72], Al[64][72];
    __shared__ unsigned short Bh[128][72], Bl[128][72];
    const int t = threadIdx.x;
    const int i0 = blockIdx.x * 64;
    const int n0 = blockIdx.y * 128;
    const int lane = t & 63, q = lane >> 4, lm = lane & 15;
    const int w = t >> 6, wm = w >> 1, wn = w & 1;
    const int ar = t >> 2, ac0 = (t & 3) << 4;
    const int bn = t >> 1, bh0 = (t & 1) << 5;
    f32x4 acc[2][4];
#pragma unroll
    for (int mt = 0; mt < 2; ++mt)
#pragma unroll
        for (int nt = 0; nt < 4; ++nt) acc[mt][nt] = (f32x4){0.f, 0.f, 0.f, 0.f};

    for (int kb = 0; kb < DIN; kb += 64) {
        __syncthreads();
        {
            const float4* xp = (const float4*)(x + (size_t)(i0 + ar) * DIN + kb + ac0);
#pragma unroll
            for (int u = 0; u < 4; ++u) {
                float4 v = xp[u];
                unsigned short h0 = f2bf(v.x), h1 = f2bf(v.y), h2 = f2bf(v.z), h3 = f2bf(v.w);
                unsigned short l0 = f2bf(v.x - bf2f(h0)), l1 = f2bf(v.y - bf2f(h1));
                unsigned short l2 = f2bf(v.z - bf2f(h2)), l3 = f2bf(v.w - bf2f(h3));
                *(uint2*)&Ah[ar][ac0 + u * 4] =
                    make_uint2((unsigned)h0 | ((unsigned)h1 << 16), (unsigned)h2 | ((unsigned)h3 << 16));
                *(uint2*)&Al[ar][ac0 + u * 4] =
                    make_uint2((unsigned)l0 | ((unsigned)l1 << 16), (unsigned)l2 | ((unsigned)l3 << 16));
            }
            const float4* wp = (const float4*)(W + (size_t)(n0 + bn) * DIN + kb + bh0);
#pragma unroll
            for (int u = 0; u < 8; ++u) {
                float4 v = wp[u];
                unsigned short h0 = f2bf(v.x), h1 = f2bf(v.y), h2 = f2bf(v.z), h3 = f2bf(v.w);
                unsigned short l0 = f2bf(v.x - bf2f(h0)), l1 = f2bf(v.y - bf2f(h1));
                unsigned short l2 = f2bf(v.z - bf2f(h2)), l3 = f2bf(v.w - bf2f(h3));
                *(uint2*)&Bh[bn][bh0 + u * 4] =
                    make_uint2((unsigned)h0 | ((unsigned)h1 << 16), (unsigned)h2 | ((unsigned)h3 << 16));
                *(uint2*)&Bl[bn][bh0 + u * 4] =
                    make_uint2((unsigned)l0 | ((unsigned)l1 << 16), (unsigned)l2 | ((unsigned)l3 << 16));
            }
        }
        __syncthreads();
#pragma unroll
        for (int ks = 0; ks < 64; ks += 32) {
            short8 fa_h[2], fa_l[2], fb_h[4], fb_l[4];
#pragma unroll
            for (int mt = 0; mt < 2; ++mt) {
                int r = wm * 32 + mt * 16 + lm;
                fa_h[mt] = *(const short8*)&Ah[r][ks + q * 8];
                fa_l[mt] = *(const short8*)&Al[r][ks + q * 8];
            }
#pragma unroll
            for (int nt = 0; nt < 4; ++nt) {
                int c = wn * 64 + nt * 16 + lm;
                fb_h[nt] = *(const short8*)&Bh[c][ks + q * 8];
                fb_l[nt] = *(const short8*)&Bl[c][ks + q * 8];
            }
#pragma unroll
            for (int mt = 0; mt < 2; ++mt)
#pragma unroll
                for (int nt = 0; nt < 4; ++nt) {
                    acc[mt][nt] = __builtin_amdgcn_mfma_f32_16x16x32_bf16(fa_h[mt], fb_h[nt], acc[mt][nt], 0, 0, 0);
                    acc[mt][nt] = __builtin_amdgcn_mfma_f32_16x16x32_bf16(fa_h[mt], fb_l[nt], acc[mt][nt], 0, 0, 0);
                    acc[mt][nt] = __builtin_amdgcn_mfma_f32_16x16x32_bf16(fa_l[mt], fb_h[nt], acc[mt][nt], 0, 0, 0);
                }
        }
    }
#pragma unroll
    for (int mt = 0; mt < 2; ++mt)
#pragma unroll
        for (int nt = 0; nt < 4; ++nt)
#pragma unroll
            for (int rr = 0; rr < 4; ++rr) {
                int row = i0 + wm * 32 + mt * 16 + q * 4 + rr;
                int col = n0 + wn * 64 + nt * 16 + lm;
                h[(size_t)row * DD + col] = acc[mt][nt][rr];
            }
}

// ---------------------------------------------------------------------------
// K3a: s_j = h[j,:] . a[256:512]; one wave per row; block partial max.
// ---------------------------------------------------------------------------
__global__ __launch_bounds__(256) void k_s(
        const float* __restrict__ h, const float* __restrict__ a,
        float* __restrict__ s, float* __restrict__ pmax) {
    __shared__ float wmax[4];
    const int t = threadIdx.x, w = t >> 6, lane = t & 63;
    const int row = blockIdx.x * 4 + w;
    float4 hv = *(const float4*)(h + (size_t)row * DD + lane * 4);
    float4 av = *(const float4*)(a + DD + lane * 4);
    float d = hv.x * av.x + hv.y * av.y + hv.z * av.z + hv.w * av.w;
#pragma unroll
    for (int off = 32; off; off >>= 1) d += __shfl_down(d, off);
    if (lane == 0) { s[row] = d; wmax[w] = d; }
    __syncthreads();
    if (t == 0)
        pmax[blockIdx.x] = fmaxf(fmaxf(wmax[0], wmax[1]), fmaxf(wmax[2], wmax[3]));
}

// ---------------------------------------------------------------------------
// K3b: global max of pmax[2048], then e_j = exp(s_j - M).
// ---------------------------------------------------------------------------
__global__ __launch_bounds__(1024) void k_e(
        const float* __restrict__ s, const float* __restrict__ pmax,
        float* __restrict__ e) {
    __shared__ float red[1024];
    const int t = threadIdx.x;
    red[t] = fmaxf(pmax[t], pmax[t + 1024]);
    __syncthreads();
    for (int off = 512; off; off >>= 1) {
        if (t < off) red[t] = fmaxf(red[t], red[t + off]);
        __syncthreads();
    }
    float M = red[0];
    for (int j = t; j < NR; j += 1024) e[j] = expf(s[j] - M);
}

// ---------------------------------------------------------------------------
// K4: g_t[d][j] = bf16(e_j * h[j][d])  (transposed, bf16) via LDS tile.
// ---------------------------------------------------------------------------
__global__ __launch_bounds__(256) void k_gt(
        const float* __restrict__ h, const float* __restrict__ e,
        unsigned short* __restrict__ gt) {
    __shared__ float tile[64][68];
    const int t = threadIdx.x;
    const int j0 = blockIdx.x * 64, d0 = blockIdx.y * 64;
    const int r = t >> 4, c4 = (t & 15) * 4;
#pragma unroll
    for (int rr = 0; rr < 4; ++rr) {
        int row = r + rr * 16;
        *(float4*)&tile[row][c4] = *(const float4*)(h + (size_t)(j0 + row) * DD + d0 + c4);
    }
    __syncthreads();
    float4 ev = *(const float4*)(e + j0 + c4);
#pragma unroll
    for (int rr = 0; rr < 4; ++rr) {
        int dd = r + rr * 16;
        unsigned short o0 = f2bf(ev.x * tile[c4 + 0][dd]);
        unsigned short o1 = f2bf(ev.y * tile[c4 + 1][dd]);
        unsigned short o2 = f2bf(ev.z * tile[c4 + 2][dd]);
        unsigned short o3 = f2bf(ev.w * tile[c4 + 3][dd]);
        *(uint2*)(gt + (size_t)(d0 + dd) * NR + j0 + c4) =
            make_uint2((unsigned)o0 | ((unsigned)o1 << 16), (unsigned)o2 | ((unsigned)o3 << 16));
    }
}

// ---------------------------------------------------------------------------
// K5 (fused): 32 rows/block, full K=8192, grid 256 = 1 block/CU, block 1024.
// Changes this round (R1):
//   (1) adj prefetch loads + alpha/out0 stores are NON-TEMPORAL (evict-first)
//       so the 512 MiB of streaming adj/alpha traffic stops evicting the
//       4 MiB gt table from per-XCD L2 — fb loads should become L2 hits.
//   (2) barrier (b) is a RAW s_barrier with an explicit lgkmcnt(0)-only wait:
//       __syncthreads() would emit s_waitcnt vmcnt(0) and drain the adj
//       prefetch just issued (~900 cyc exposed HBM latency × 64 iters).
//       The prefetch now genuinely stays in flight across the barrier and
//       is only waited at its consumption (top of next iteration).
//       Barrier (a) stays __syncthreads(): no outstanding vmem there, its
//       implicit drain is free, and it keeps full compiler-verified safety
//       for the read->write hand-off on As_f.
// ---------------------------------------------------------------------------
__global__ __launch_bounds__(1024, 4) void k_fused(
        const int* __restrict__ adj, const unsigned short* __restrict__ gt,
        const float* __restrict__ e, float* __restrict__ out0,
        float* __restrict__ alpha) {
    // A fragments: [mt][s][lane*8+j] shorts = 2*4*512 shorts = 8 KB
    __shared__ unsigned short As_f[2 * 4 * 512];
    __shared__ float dnm_s[32];
    const int t = threadIdx.x;
    const int row0 = blockIdx.x * 32;
    const int lane = t & 63, q = lane >> 4, lm = lane & 15;
    const int w = t >> 6;                     // 16 waves, each owns 16 cols
    const int ar = t >> 5, c = t & 31;        // staging: row ar, cols c*4..+3

    // fragment-layout write offset (constant per thread), in shorts:
    //   k_local = 4c+u -> s=c>>3, q'=(c>>1)&3, j=(c&1)*4+u, m=ar&15, mt=ar>>4
    const int woff = (ar >> 4) * 2048 + (c >> 3) * 512 +
                     (((c >> 1) & 3) * 16 + (ar & 15)) * 8 + (c & 1) * 4;

    f32x4 acc[2];
    acc[0] = (f32x4){0.f, 0.f, 0.f, 0.f};
    acc[1] = (f32x4){0.f, 0.f, 0.f, 0.f};
    unsigned bits[8] = {0, 0, 0, 0, 0, 0, 0, 0};
    float dsum = 0.f;

    const int* ap = adj + (size_t)(row0 + ar) * NR + c * 4;
    const float* ep = e + c * 4;
    // B fragment base: row n = w*16+lm of gt, k-offset q*8
    const unsigned short* gb = gt + (size_t)(w * 16 + lm) * NR + q * 8;

    i32x4 pa = __builtin_nontemporal_load((const i32x4*)ap);  // prefetch tile 0

#pragma unroll 2
    for (int it = 0; it < 64; ++it) {
        // ---- convert prefetched adj (registers) ----
        float4 ev = *(const float4*)(ep + it * 128);
        unsigned p0 = (pa.x ? 0x3F80u : 0u) | (pa.y ? 0x3F800000u : 0u);
        unsigned p1 = (pa.z ? 0x3F80u : 0u) | (pa.w ? 0x3F800000u : 0u);
        dsum += (pa.x ? ev.x : 0.f) + (pa.y ? ev.y : 0.f) +
                (pa.z ? ev.z : 0.f) + (pa.w ? ev.w : 0.f);
        unsigned nib = (pa.x ? 1u : 0u) | (pa.y ? 2u : 0u) |
                       (pa.z ? 4u : 0u) | (pa.w ? 8u : 0u);
        bits[it >> 3] |= nib << ((it & 7) * 4);
        __syncthreads();                       // (a) prev compute done with As_f
        *(uint2*)&As_f[woff] = make_uint2(p0, p1);
        // issue next prefetch NOW — with the raw barrier below it truly stays
        // in flight across (b) + the whole compute phase
        pa = __builtin_nontemporal_load(
                 (const i32x4*)(ap + (size_t)(((it + 1) & 63) * 128)));
        // (b): own ds_write visible, then barrier WITHOUT vmcnt drain
        asm volatile("s_waitcnt lgkmcnt(0)" ::: "memory");
        __builtin_amdgcn_s_barrier();
        __builtin_amdgcn_sched_barrier(0);     // keep ds_reads below the barrier
        // ---- compute: A frags from LDS (lane-linear), B frags from global ----
#pragma unroll
        for (int s = 0; s < 4; ++s) {
            short8 fa0 = *(const short8*)&As_f[s * 512 + lane * 8];
            short8 fa1 = *(const short8*)&As_f[2048 + s * 512 + lane * 8];
            short8 fb = *(const short8*)(gb + (size_t)it * 128 + s * 32);
            acc[0] = __builtin_amdgcn_mfma_f32_16x16x32_bf16(fa0, fb, acc[0], 0, 0, 0);
            acc[1] = __builtin_amdgcn_mfma_f32_16x16x32_bf16(fa1, fb, acc[1], 0, 0, 0);
        }
    }

    // ---- denom: 32 lanes (same ar) share a row; they sit in one half-wave ----
    dsum += __shfl_xor(dsum, 1);
    dsum += __shfl_xor(dsum, 2);
    dsum += __shfl_xor(dsum, 4);
    dsum += __shfl_xor(dsum, 8);
    dsum += __shfl_xor(dsum, 16);
    if (c == 0) dnm_s[ar] = dsum;
    __syncthreads();
    if (t < 32) dnm_s[t] = 1.0f / dnm_s[t];
    __syncthreads();

    // ---- out0 = elu(num * invd) ----
#pragma unroll
    for (int mt = 0; mt < 2; ++mt)
#pragma unroll
        for (int rr = 0; rr < 4; ++rr) {
            int r = mt * 16 + q * 4 + rr;
            int cc = w * 16 + lm;
            float z = acc[mt][rr] * dnm_s[r];
            float o = z > 0.f ? z : expm1f(z);
            __builtin_nontemporal_store(o, &out0[(size_t)(row0 + r) * DD + cc]);
        }

    // ---- alpha replay from VGPR bitmask (non-temporal streaming stores) ----
    const float invr = dnm_s[ar];
    float* arow = alpha + (size_t)(row0 + ar) * NR + c * 4;
#pragma unroll 4
    for (int it = 0; it < 64; ++it) {
        unsigned nib = (bits[it >> 3] >> ((it & 7) * 4)) & 15u;
        float4 ev = *(const float4*)(ep + it * 128);
        f32x4 o;
        o.x = (nib & 1u) ? ev.x * invr : 0.f;
        o.y = (nib & 2u) ? ev.y * invr : 0.f;
        o.z = (nib & 4u) ? ev.z * invr : 0.f;
        o.w = (nib & 8u) ? ev.w * invr : 0.f;
        __builtin_nontemporal_store(o, (f32x4*)(arow + (size_t)it * 128));
    }
}

// ---------------------------------------------------------------------------
extern "C" void kernel_launch(void* const* d_in, const int* in_sizes, int n_in,
                              void* d_out, int out_size, void* d_ws, size_t ws_size,
                              hipStream_t stream) {
    const float* x = (const float*)d_in[0];
    const int* adj = (const int*)d_in[1];
    const float* W = (const float*)d_in[2];
    const float* a = (const float*)d_in[3];
    float* out0 = (float*)d_out;
    float* alpha = (float*)d_out + (size_t)NR * DD;

    char* ws = (char*)d_ws;
    float* h            = (float*)(ws + 0);          //  8,388,608 B
    float* s            = (float*)(ws + 8388608);    //     32,768 B
    float* pmax         = (float*)(ws + 8421376);    //      8,192 B
    float* e            = (float*)(ws + 8429568);    //     32,768 B
    unsigned short* gt  = (unsigned short*)(ws + 8462336);  // 4,194,304 B (end ~12.7 MB)

    k_gemm_h<<<dim3(128, 2), 256, 0, stream>>>(x, W, h);
    k_s<<<2048, 256, 0, stream>>>(h, a, s, pmax);
    k_e<<<1, 1024, 0, stream>>>(s, pmax, e);
    k_gt<<<dim3(128, 4), 256, 0, stream>>>(h, e, gt);
    k_fused<<<256, 1024, 0, stream>>>(adj, gt, e, out0, alpha);
}